// Round 12
// baseline (133.136 us; speedup 1.0000x reference)
//
#include <hip/hip_runtime.h>
#include <hip/hip_bf16.h>
#include <math.h>

// ---------------------------------------------------------------------------
// Sketched CNN-MNIST forward, MFMA end-to-end, TWO kernels.
// ALGEBRA (R4..R11): out = h @ W3.T = h' @ w3.T,
//   h'[b,q] = sum_{k: hi3[k]=q} h[b,k]*s3[k]   (s3 = +-1 exactly)
// R11: bucket-reduce in k_conv epilogue, atomic-free (scatter to pos[k] in
// LDS -> parallel segment sums). R12: k_fc FUSED into k_conv -- the 4x128 h'
// tile never leaves LDS: fc1 = M=16-padded MFMA vs dense W3d (rows 4-15
// zeroed), fc2 = 2 waves/img x 5 classes shuffle-reduce, log_softmax by 4
// threads, write `out` directly. h2 and k_fc are GONE.
//
// BLOCK-SIZE LESSON (R10): 2 img/block raised occupancy 44->64% but SLOWED
// k_conv 43->50us (B-loads per MFMA doubled; issue-bound). 4 img/block stays.
// BANK LESSON (R7): s_h1 stride 1160 is minimal conflict-free for conv2's
// ds_read_b128. REGISTER NOTE (R1/R2): never demand 8 waves/EU; watch
// WRITE_SIZE (now expected ~170 KB = out only; >>1 MB = spill).
// HARNESS NOTE (R6): __amd_rocclr_fillBufferAligned re-poisons the workspace
// every iteration (~41us at full HBM BW). Fixed overhead.
// ---------------------------------------------------------------------------

typedef __attribute__((ext_vector_type(8))) short bf16x8;
typedef __attribute__((ext_vector_type(4))) float f32x4;

static __device__ inline ushort f2bfu(float v) {
    union { __hip_bfloat16 h; ushort u; } cv;
    cv.h = __float2bfloat16(v);
    return cv.u;
}

static __device__ inline float bfu2f(ushort u) {
    union { ushort u; __hip_bfloat16 h; } cv;
    cv.u = u;
    return __bfloat162float(cv.h);
}

// ws layout (bytes):
//   wc1f bf16 [2 nt][64 lane][8]   frag-major      [0,       2048)
//   wc1s bf16 [2 nt][64 lane][8]   shifted         [2048,    4096)
//   wc2f bf16 [25 tap][4 nt][64 lane][8ic]         [4096,    106496)
//   W3d  bf16 [32 ntile][4 kt][64 lane][8]  DENSE  [106496,  237568)
//   seg  int  [129]  bucket starts (prefix sum)    [237568,  238084)
//   pos  int  [1024] k -> bucket-sorted slot       [238592,  242688)

// Blocks 0..231: 4 threads per 16B fragment (2 elements each); branch 3 is a
// plain dense-w3 repack (no gather). Block 232: seg/pos builder.
__global__ __launch_bounds__(256)
void k_reconstruct(const float* __restrict__ w1, const float* __restrict__ w2,
                   const float* __restrict__ w3,
                   const int* __restrict__ hi1, const int* __restrict__ hi2,
                   const int* __restrict__ hi3,
                   const float* __restrict__ s1, const float* __restrict__ s2,
                   __hip_bfloat16* __restrict__ wc1f,
                   __hip_bfloat16* __restrict__ wc1s,
                   __hip_bfloat16* __restrict__ wc2f,
                   __hip_bfloat16* __restrict__ W3d,
                   int* __restrict__ seg, int* __restrict__ pos) {
    if (blockIdx.x == 232) {               // seg/pos builder, one block
        __shared__ int scnt[128];
        __shared__ int sincl[128];
        __shared__ int sseg[129];
        const int u = threadIdx.x;
        if (u < 128) scnt[u] = 0;
        __syncthreads();
        int qq[4], rk[4];
        #pragma unroll
        for (int j = 0; j < 4; ++j) {
            int k = u * 4 + j;             // 0..1023
            qq[j] = hi3[k];
            rk[j] = atomicAdd(&scnt[qq[j]], 1);
        }
        __syncthreads();
        if (u < 128) {                     // waves 0,1 fully active: shfl scan
            int v = scnt[u];
            #pragma unroll
            for (int d = 1; d < 64; d <<= 1) {
                int t2 = __shfl_up(v, d);
                if ((u & 63) >= d) v += t2;
            }
            sincl[u] = v;
        }
        __syncthreads();
        if (u < 128) {
            int base = (u >= 64) ? sincl[63] : 0;
            sseg[u + 1] = base + sincl[u];
        }
        if (u == 0) sseg[0] = 0;
        __syncthreads();
        #pragma unroll
        for (int j = 0; j < 4; ++j) {
            int k = u * 4 + j;
            pos[k] = sseg[qq[j]] + rk[j];
        }
        if (u < 129) seg[u] = sseg[u];
        return;
    }
    const int t = blockIdx.x * blockDim.x + threadIdx.x;
    const int f = t >> 2;            // fragment id
    const int j0 = (t & 3) * 2;      // this thread's 2 elements of the 8
    if (f < 256) {                         // conv1 normal (f<128) / shifted
        const bool shifted = f >= 128;
        const int u = f & 127;
        const int nt = u >> 6, lane = u & 63;
        const int quad = lane >> 4, l15 = lane & 15;
        const int oc = nt * 16 + l15;
        ushort rr[2];
        #pragma unroll
        for (int jj = 0; jj < 2; ++jj) {
            int tt = quad * 8 + j0 + jj;
            int ki = (tt * 43) >> 8;       // tt / 6
            int kj = tt - 6 * ki;
            float v = 0.f;
            if (!shifted && ki < 5 && kj < 5) {
                int fi = ki * 5 + kj;
                v = w1[oc * 128 + hi1[fi]] * s1[fi];
            } else if (shifted && ki < 5 && kj >= 1 && kj <= 5) {
                int fi = ki * 5 + (kj - 1);
                v = w1[oc * 128 + hi1[fi]] * s1[fi];
            }
            rr[jj] = f2bfu(v);
        }
        *(uint*)((ushort*)(shifted ? wc1s : wc1f) + (size_t)u * 8 + j0) =
            (uint)rr[0] | ((uint)rr[1] << 16);
    } else if (f < 6656) {                 // conv2: [tap][nt][lane][8ic]
        const int u = f - 256;
        const int l15 = u & 15, quad = (u >> 4) & 3;
        const int ntA = (u >> 6) & 3, tap = u >> 8;
        const int oc = ntA * 16 + l15;
        ushort rr[2];
        #pragma unroll
        for (int jj = 0; jj < 2; ++jj) {
            int ic = quad * 8 + j0 + jj;
            int fi = ic * 25 + tap;
            rr[jj] = f2bfu(w2[oc * 128 + hi2[fi]] * s2[fi]);
        }
        *(uint*)((ushort*)wc2f + (size_t)u * 8 + j0) =
            (uint)rr[0] | ((uint)rr[1] << 16);
    } else if (f < 14848) {                // w3 DENSE repack: [ntile][kt][lane][8]
        const int u = f - 6656;
        const int l15 = u & 15, quad = (u >> 4) & 3;
        const int kt = (u >> 6) & 3, ntile = u >> 8;
        const int n = ntile * 16 + l15;
        ushort rr[2];
        #pragma unroll
        for (int jj = 0; jj < 2; ++jj) {
            int k = kt * 32 + quad * 8 + j0 + jj;   // k in [0,128)
            rr[jj] = f2bfu(w3[n * 128 + k]);
        }
        *(uint*)((ushort*)W3d + (size_t)u * 8 + j0) =
            (uint)rr[0] | ((uint)rr[1] << 16);
    }
}

// 4 images per block, 8 waves, 3 blocks/CU (LDS ~44 KB).
// conv1 -> s_h1 -> conv2 taps -> scatter to pos[k] (write-once) ->
// segment sums -> h' bf16 tile -> fc1 MFMA (M=16 pad, rows 0-3 = images) ->
// fc2 shuffle-reduce -> log_softmax -> out.  All in one kernel.
__global__ __launch_bounds__(512, 6)
void k_conv(const float* __restrict__ x,
            const __hip_bfloat16* __restrict__ wc1f,
            const __hip_bfloat16* __restrict__ wc1s,
            const __hip_bfloat16* __restrict__ wc2f,
            const __hip_bfloat16* __restrict__ W3d,
            const float* __restrict__ b1, const float* __restrict__ b2,
            const int* __restrict__ pos, const int* __restrict__ seg,
            const float* __restrict__ s3, const float* __restrict__ b3,
            const float* __restrict__ fc2w, const float* __restrict__ fc2b,
            float* __restrict__ out) {
    __shared__ __align__(16) ushort s_xb[4 * 816];     // bf16 images (+pad)
    __shared__ __align__(16) ushort s_h1[16 * 1160];   // sectioned, 37.1 KB
    __shared__ float s_lg[4][12];                      // logits

    const int tid = threadIdx.x;
    const int b0 = blockIdx.x * 4;
    const int wave = tid >> 6, lane = tid & 63;
    const int l15 = lane & 15, quad = lane >> 4;

    // ---- stage 4 images as bf16 (coalesced float4) ----
    {
        const float4* xg = (const float4*)(x + (size_t)b0 * 784);
        for (int i = tid; i < 784; i += 512) {
            float4 v = xg[i];
            int img = i / 196;
            int p = (i - img * 196) * 4;
            ushort* dst = &s_xb[img * 816 + p];
            dst[0] = f2bfu(v.x); dst[1] = f2bfu(v.y);
            dst[2] = f2bfu(v.z); dst[3] = f2bfu(v.w);
        }
        if (tid < 128) {                    // zero pad (read by pad taps, w=0)
            int img = tid >> 5, k = tid & 31;
            s_xb[img * 816 + 784 + k] = 0;
        }
    }

    // conv1 B-fragments (frag-major: coalesced 1 KB wave loads)
    bf16x8 bw1[2], bw1s[2];
    float bb1[2];
    #pragma unroll
    for (int nt = 0; nt < 2; ++nt) {
        bw1[nt]  = *(const bf16x8*)((const ushort*)wc1f + (nt * 64 + lane) * 8);
        bw1s[nt] = *(const bf16x8*)((const ushort*)wc1s + (nt * 64 + lane) * 8);
        bb1[nt] = b1[nt * 16 + l15];
    }
    __syncthreads();

    // ---- conv1 via MFMA: wave = (img, half). M=576 pool-grouped, N=32 ----
    {
        const int img = wave >> 1, half = wave & 1;
        const int sub = l15 & 3;
        const ushort* srcImg = s_xb + img * 816;
        int offr[4];
        #pragma unroll
        for (int r = 0; r < 4; ++r) {
            int t = quad * 8 + 2 * r;          // even
            int row = (t * 43) >> 8;           // t / 6
            int col = t - 6 * row;             // even
            offr[r] = row * 28 + col;          // even
        }
        const int g0 = l15 >> 3, r0 = l15 & 7;
        #pragma unroll
        for (int ii = 0; ii < 18; ++ii) {
            const int i = half * 18 + ii;
            const int pb = 4 * i + (l15 >> 2);
            const int pi = (pb * 171) >> 11;   // pb / 12
            const int pj = pb - 12 * pi;
            const int base_e = (2 * pi + (sub >> 1)) * 28 + 2 * pj;   // even
            const ushort* p0 = srcImg + base_e;
            union { bf16x8 v; uint u[4]; } A;
            A.u[0] = *(const uint*)(p0 + offr[0]);
            A.u[1] = *(const uint*)(p0 + offr[1]);
            A.u[2] = *(const uint*)(p0 + offr[2]);
            A.u[3] = *(const uint*)(p0 + offr[3]);
            f32x4 z = {0.f, 0.f, 0.f, 0.f};
            f32x4 ce0 = __builtin_amdgcn_mfma_f32_16x16x32_bf16(A.v, bw1[0],  z, 0, 0, 0);
            f32x4 co0 = __builtin_amdgcn_mfma_f32_16x16x32_bf16(A.v, bw1s[0], z, 0, 0, 0);
            f32x4 ce1 = __builtin_amdgcn_mfma_f32_16x16x32_bf16(A.v, bw1[1],  z, 0, 0, 0);
            f32x4 co1 = __builtin_amdgcn_mfma_f32_16x16x32_bf16(A.v, bw1s[1], z, 0, 0, 0);
            const int pbo = 4 * i + quad;
            float m0 = fmaxf(fmaxf(ce0[0], co0[1]), fmaxf(ce0[2], co0[3]));
            float m1 = fmaxf(fmaxf(ce1[0], co1[1]), fmaxf(ce1[2], co1[3]));
            // oc = l15 -> section img*4 + g0 ; oc = 16+l15 -> section img*4+2+g0
            s_h1[(img * 4 + g0) * 1160 + pbo * 8 + r0]     = f2bfu(fmaxf(m0 + bb1[0], 0.f));
            s_h1[(img * 4 + 2 + g0) * 1160 + pbo * 8 + r0] = f2bfu(fmaxf(m1 + bb1[1], 0.f));
        }
    }
    __syncthreads();

    // ---- conv2: 25 tap-GEMMs, K=ic=32; wave = (pool-row, n-half), 4 images
    //      4 A ds_reads + 2 coalesced B loads -> 8 MFMA per tap ----
    const int pr = wave >> 1, nh = wave & 1;
    const int sub2 = l15 & 3;
    const int ci2 = 2 * pr + (sub2 >> 1);
    const int cj2 = 2 * (l15 >> 2) + (sub2 & 1);
    const int posBase = (ci2 * 12 + cj2) * 8;

    f32x4 acc[4][2];                       // [img][ntl]
    float bb2[2];
    #pragma unroll
    for (int ntl = 0; ntl < 2; ++ntl) {
        bb2[ntl] = b2[(nh * 2 + ntl) * 16 + l15];
        #pragma unroll
        for (int img = 0; img < 4; ++img)
            acc[img][ntl] = (f32x4){0.f, 0.f, 0.f, 0.f};
    }

    #pragma unroll
    for (int tap = 0; tap < 25; ++tap) {
        const int ki = tap / 5, kj = tap % 5;          // compile-time
        const int off = (ki * 12 + kj) * 8;
        bf16x8 a[4];
        #pragma unroll
        for (int img = 0; img < 4; ++img)
            a[img] = *(const bf16x8*)&s_h1[(img * 4 + quad) * 1160 + posBase + off];
        #pragma unroll
        for (int ntl = 0; ntl < 2; ++ntl) {
            bf16x8 bf = *(const bf16x8*)((const ushort*)wc2f +
                          ((tap * 4 + nh * 2 + ntl) * 64 + lane) * 8);
            #pragma unroll
            for (int img = 0; img < 4; ++img)
                acc[img][ntl] = __builtin_amdgcn_mfma_f32_16x16x32_bf16(
                    a[img], bf, acc[img][ntl], 0, 0, 0);
        }
    }

    __syncthreads();                       // all waves done reading s_h1

    // ---- epilogue 1: pool+relu+pre-scale, scatter into s_h1-reused LDS at
    //      bucket-sorted slot pos[k] (write-once, no atomics) ----
    ushort* s_hs = s_h1;                   // [4][1024]
    {
        const int k0 = ((nh * 2 + 0) * 16 + l15) * 16 + pr * 4 + quad;
        const int k1 = ((nh * 2 + 1) * 16 + l15) * 16 + pr * 4 + quad;
        const int p0 = pos[k0], p1 = pos[k1];
        const float sg0 = s3[k0], sg1 = s3[k1];
        #pragma unroll
        for (int img = 0; img < 4; ++img) {
            f32x4 c0 = acc[img][0];
            float m0 = fmaxf(fmaxf(c0[0], c0[1]), fmaxf(c0[2], c0[3]));
            float v0 = fmaxf(m0 + bb2[0], 0.f);
            s_hs[img * 1024 + p0] = f2bfu(v0 * sg0);
            f32x4 c1 = acc[img][1];
            float m1 = fmaxf(fmaxf(c1[0], c1[1]), fmaxf(c1[2], c1[3]));
            float v1 = fmaxf(m1 + bb2[1], 0.f);
            s_hs[img * 1024 + p1] = f2bfu(v1 * sg1);
        }
    }
    __syncthreads();

    // ---- epilogue 2: 512 parallel segment sums -> h' bf16 A-tile [4][136] ----
    ushort* s_Ab = s_h1 + 4096;            // [4][136] ushort
    {
        const int img = tid >> 7, q = tid & 127;
        const int a0 = seg[q], n = seg[q + 1] - a0;
        const ushort* src = s_hs + img * 1024 + a0;
        float v = 0.f;
        for (int i = 0; i < n; ++i) v += bfu2f(src[i]);
        s_Ab[img * 136 + q] = f2bfu(v);
    }
    __syncthreads();

    // ---- epilogue 3: fc1 via MFMA (M=16 pad: rows 0-3 = images, rest 0).
    //      wave -> ntiles 4w..4w+3 (cols 64w..64w+63), K=128 (4 kt) ----
    float* s_h3 = (float*)(s_h1 + 5632);   // [4][528] f32 (16B-aligned rows)
    {
        f32x4 facc[4];
        #pragma unroll
        for (int ntl = 0; ntl < 4; ++ntl)
            facc[ntl] = (f32x4){0.f, 0.f, 0.f, 0.f};
        #pragma unroll
        for (int kt = 0; kt < 4; ++kt) {
            bf16x8 a = (bf16x8){0, 0, 0, 0, 0, 0, 0, 0};
            if (l15 < 4)
                a = *(const bf16x8*)&s_Ab[l15 * 136 + kt * 32 + quad * 8];
            #pragma unroll
            for (int ntl = 0; ntl < 4; ++ntl) {
                bf16x8 bf = *(const bf16x8*)((const ushort*)W3d +
                              (((wave * 4 + ntl) * 4 + kt) * 64 + lane) * 8);
                facc[ntl] = __builtin_amdgcn_mfma_f32_16x16x32_bf16(
                    a, bf, facc[ntl], 0, 0, 0);
            }
        }
        // D: col = l15, row = quad*4 + r; rows 0-3 (quad==0) = images
        if (quad == 0) {
            #pragma unroll
            for (int ntl = 0; ntl < 4; ++ntl) {
                int col = wave * 64 + ntl * 16 + l15;
                float bb = b3[col];
                #pragma unroll
                for (int r = 0; r < 4; ++r)
                    s_h3[r * 528 + col] = fmaxf(facc[ntl][r] + bb, 0.f);
            }
        }
    }
    __syncthreads();

    // ---- epilogue 4: fc2. img = wave>>1, classes (wave&1)*5..+4 ----
    {
        const int img = wave >> 1;
        const float* hrow = &s_h3[img * 528];
        float4 h0 = *(const float4*)&hrow[lane * 8];
        float4 h1 = *(const float4*)&hrow[lane * 8 + 4];
        #pragma unroll
        for (int cc = 0; cc < 5; ++cc) {
            int c = (wave & 1) * 5 + cc;
            float4 w0 = *(const float4*)&fc2w[c * 512 + lane * 8];
            float4 w1 = *(const float4*)&fc2w[c * 512 + lane * 8 + 4];
            float s = h0.x * w0.x + h0.y * w0.y + h0.z * w0.z + h0.w * w0.w
                    + h1.x * w1.x + h1.y * w1.y + h1.z * w1.z + h1.w * w1.w;
            s += __shfl_down(s, 32);
            s += __shfl_down(s, 16);
            s += __shfl_down(s, 8);
            s += __shfl_down(s, 4);
            s += __shfl_down(s, 2);
            s += __shfl_down(s, 1);
            if (lane == 0) s_lg[img][c] = s + fc2b[c];
        }
    }
    __syncthreads();

    // ---- epilogue 5: log_softmax, one thread per image ----
    if (tid < 4) {
        float lg[10], mx = -1e30f;
        #pragma unroll
        for (int c = 0; c < 10; ++c) { lg[c] = s_lg[tid][c]; mx = fmaxf(mx, lg[c]); }
        float sum = 0.f;
        #pragma unroll
        for (int c = 0; c < 10; ++c) sum += expf(lg[c] - mx);
        float lse = mx + logf(sum);
        #pragma unroll
        for (int c = 0; c < 10; ++c)
            out[(size_t)(b0 + tid) * 10 + c] = lg[c] - lse;
    }
}

extern "C" void kernel_launch(void* const* d_in, const int* in_sizes, int n_in,
                              void* d_out, int out_size, void* d_ws, size_t ws_size,
                              hipStream_t stream) {
    const float* x    = (const float*)d_in[0];
    const int*   hi1  = (const int*)d_in[1];
    const int*   hi2  = (const int*)d_in[2];
    const int*   hi3  = (const int*)d_in[3];
    const float* s1   = (const float*)d_in[4];
    const float* s2   = (const float*)d_in[5];
    const float* s3   = (const float*)d_in[6];
    const float* w1   = (const float*)d_in[7];
    const float* b1   = (const float*)d_in[8];
    const float* w2   = (const float*)d_in[9];
    const float* b2   = (const float*)d_in[10];
    const float* w3   = (const float*)d_in[11];
    const float* b3   = (const float*)d_in[12];
    const float* fc2w = (const float*)d_in[13];
    const float* fc2b = (const float*)d_in[14];
    float* out = (float*)d_out;

    const int B = in_sizes[0] / 784;   // 4096

    char* ws = (char*)d_ws;
    __hip_bfloat16* wc1f = (__hip_bfloat16*)(ws + 0);
    __hip_bfloat16* wc1s = (__hip_bfloat16*)(ws + 2048);
    __hip_bfloat16* wc2f = (__hip_bfloat16*)(ws + 4096);
    __hip_bfloat16* W3d  = (__hip_bfloat16*)(ws + 106496);
    int*            seg  = (int*)(ws + 237568);
    int*            pos  = (int*)(ws + 238592);

    // blocks 0..231: fragments; block 232: seg/pos builder
    k_reconstruct<<<233, 256, 0, stream>>>(
        w1, w2, w3, hi1, hi2, hi3, s1, s2, wc1f, wc1s, wc2f, W3d, seg, pos);
    k_conv<<<B / 4, 512, 0, stream>>>(x, wc1f, wc1s, wc2f, W3d, b1, b2,
                                      pos, seg, s3, b3, fc2w, fc2b, out);
}

// Round 13
// 128.035 us; speedup vs baseline: 1.0398x; 1.0398x over previous
//
#include <hip/hip_runtime.h>
#include <hip/hip_bf16.h>
#include <math.h>

// ---------------------------------------------------------------------------
// Sketched CNN-MNIST forward, MFMA end-to-end.  [R11 optimum, restored]
// ALGEBRA (R4..R11): out = h @ W3.T = h' @ w3.T,
//   h'[b,q] = sum_{k: hi3[k]=q} h[b,k]*s3[k]   (s3 = +-1 exactly)
// R11: bucket-reduce in k_conv epilogue, atomic-free: scatter pre-scaled
// pool outputs to pos[k] in LDS (write-once permutation -> no RMW, unlike
// R5's +16us atomics), parallel segment sums -> h2 as B x 128 (1 MB).
// k_fc: K=128 GEMM vs dense w3. seg/pos built by one k_reconstruct block.
//
// FUSION LESSON (R12): folding fc1/fc2 into k_conv = +12us (M=16 MFMA with
// 4 useful rows, 4x W3d re-reads, 4 barriers) > the ~8.5us k_fc costs.
// BLOCK-SIZE LESSON (R10): 2 img/block raised occupancy 44->64% but SLOWED
// k_conv 43->50us (B-loads per MFMA doubled; issue-bound). 4 img/block.
// BANK LESSON (R7): s_h1 stride 1160 is minimal conflict-free for conv2's
// ds_read_b128 reads (critical path); write conflicts are latency-tolerant.
// REGISTER NOTE (R1/R2): never demand 8 waves/EU via launch_bounds (caps
// unified VGPR+AGPR at 64 -> 42 MB scratch spill). Watch WRITE_SIZE (~1 MB).
// HARNESS NOTE (R6): __amd_rocclr_fillBufferAligned re-poisons the 256 MB
// workspace every iteration (~41us at full HBM BW) + dozens of small
// memsets from reset(). Fixed overhead, not removable kernel-side.
// ---------------------------------------------------------------------------

typedef __attribute__((ext_vector_type(8))) short bf16x8;
typedef __attribute__((ext_vector_type(4))) float f32x4;

static __device__ inline ushort f2bfu(float v) {
    union { __hip_bfloat16 h; ushort u; } cv;
    cv.h = __float2bfloat16(v);
    return cv.u;
}

static __device__ inline float bfu2f(ushort u) {
    union { ushort u; __hip_bfloat16 h; } cv;
    cv.u = u;
    return __bfloat162float(cv.h);
}

// ws layout (bytes):
//   wc1f bf16 [2 nt][64 lane][8]   frag-major      [0,       2048)
//   wc1s bf16 [2 nt][64 lane][8]   shifted         [2048,    4096)
//   wc2f bf16 [25 tap][4 nt][64 lane][8ic]         [4096,    106496)
//   W3d  bf16 [32 ntile][4 kt][64 lane][8]  DENSE  [106496,  237568)
//   seg  int  [129]  bucket starts (prefix sum)    [237568,  238084)
//   pos  int  [1024] k -> bucket-sorted slot       [238592,  242688)
//   h2   bf16 [B][128]  bucketed h'                [1155072, +B*256)

// Blocks 0..231: 4 threads per 16B fragment (2 elements each); branch 3 is a
// plain dense-w3 repack (no gather). Block 232: seg/pos builder.
__global__ __launch_bounds__(256)
void k_reconstruct(const float* __restrict__ w1, const float* __restrict__ w2,
                   const float* __restrict__ w3,
                   const int* __restrict__ hi1, const int* __restrict__ hi2,
                   const int* __restrict__ hi3,
                   const float* __restrict__ s1, const float* __restrict__ s2,
                   __hip_bfloat16* __restrict__ wc1f,
                   __hip_bfloat16* __restrict__ wc1s,
                   __hip_bfloat16* __restrict__ wc2f,
                   __hip_bfloat16* __restrict__ W3d,
                   int* __restrict__ seg, int* __restrict__ pos) {
    if (blockIdx.x == 232) {               // seg/pos builder, one block
        __shared__ int scnt[128];
        __shared__ int sincl[128];
        __shared__ int sseg[129];
        const int u = threadIdx.x;
        if (u < 128) scnt[u] = 0;
        __syncthreads();
        int qq[4], rk[4];
        #pragma unroll
        for (int j = 0; j < 4; ++j) {
            int k = u * 4 + j;             // 0..1023
            qq[j] = hi3[k];
            rk[j] = atomicAdd(&scnt[qq[j]], 1);
        }
        __syncthreads();
        if (u < 128) {                     // waves 0,1 fully active: shfl scan
            int v = scnt[u];
            #pragma unroll
            for (int d = 1; d < 64; d <<= 1) {
                int t2 = __shfl_up(v, d);
                if ((u & 63) >= d) v += t2;
            }
            sincl[u] = v;
        }
        __syncthreads();
        if (u < 128) {
            int base = (u >= 64) ? sincl[63] : 0;
            sseg[u + 1] = base + sincl[u];
        }
        if (u == 0) sseg[0] = 0;
        __syncthreads();
        #pragma unroll
        for (int j = 0; j < 4; ++j) {
            int k = u * 4 + j;
            pos[k] = sseg[qq[j]] + rk[j];
        }
        if (u < 129) seg[u] = sseg[u];
        return;
    }
    const int t = blockIdx.x * blockDim.x + threadIdx.x;
    const int f = t >> 2;            // fragment id
    const int j0 = (t & 3) * 2;      // this thread's 2 elements of the 8
    if (f < 256) {                         // conv1 normal (f<128) / shifted
        const bool shifted = f >= 128;
        const int u = f & 127;
        const int nt = u >> 6, lane = u & 63;
        const int quad = lane >> 4, l15 = lane & 15;
        const int oc = nt * 16 + l15;
        ushort rr[2];
        #pragma unroll
        for (int jj = 0; jj < 2; ++jj) {
            int tt = quad * 8 + j0 + jj;
            int ki = (tt * 43) >> 8;       // tt / 6
            int kj = tt - 6 * ki;
            float v = 0.f;
            if (!shifted && ki < 5 && kj < 5) {
                int fi = ki * 5 + kj;
                v = w1[oc * 128 + hi1[fi]] * s1[fi];
            } else if (shifted && ki < 5 && kj >= 1 && kj <= 5) {
                int fi = ki * 5 + (kj - 1);
                v = w1[oc * 128 + hi1[fi]] * s1[fi];
            }
            rr[jj] = f2bfu(v);
        }
        *(uint*)((ushort*)(shifted ? wc1s : wc1f) + (size_t)u * 8 + j0) =
            (uint)rr[0] | ((uint)rr[1] << 16);
    } else if (f < 6656) {                 // conv2: [tap][nt][lane][8ic]
        const int u = f - 256;
        const int l15 = u & 15, quad = (u >> 4) & 3;
        const int ntA = (u >> 6) & 3, tap = u >> 8;
        const int oc = ntA * 16 + l15;
        ushort rr[2];
        #pragma unroll
        for (int jj = 0; jj < 2; ++jj) {
            int ic = quad * 8 + j0 + jj;
            int fi = ic * 25 + tap;
            rr[jj] = f2bfu(w2[oc * 128 + hi2[fi]] * s2[fi]);
        }
        *(uint*)((ushort*)wc2f + (size_t)u * 8 + j0) =
            (uint)rr[0] | ((uint)rr[1] << 16);
    } else if (f < 14848) {                // w3 DENSE repack: [ntile][kt][lane][8]
        const int u = f - 6656;
        const int l15 = u & 15, quad = (u >> 4) & 3;
        const int kt = (u >> 6) & 3, ntile = u >> 8;
        const int n = ntile * 16 + l15;
        ushort rr[2];
        #pragma unroll
        for (int jj = 0; jj < 2; ++jj) {
            int k = kt * 32 + quad * 8 + j0 + jj;   // k in [0,128)
            rr[jj] = f2bfu(w3[n * 128 + k]);
        }
        *(uint*)((ushort*)W3d + (size_t)u * 8 + j0) =
            (uint)rr[0] | ((uint)rr[1] << 16);
    }
}

// 4 images per block, 8 waves, 3 blocks/CU (LDS 43.6 KB).
// h1 layout: section s = img*4 + (ic>>3); s_h1[s*1160 + pos*8 + (ic&7)].
// Epilogue: scatter pre-scaled pool outputs into s_h1-reused LDS at pos[k]
// (bucket-sorted, write-once), then parallel segment-sums -> h2[b][q] (Bx128).
__global__ __launch_bounds__(512, 6)
void k_conv(const float* __restrict__ x,
            const __hip_bfloat16* __restrict__ wc1f,
            const __hip_bfloat16* __restrict__ wc1s,
            const __hip_bfloat16* __restrict__ wc2f,
            const float* __restrict__ b1, const float* __restrict__ b2,
            const int* __restrict__ pos, const int* __restrict__ seg,
            const float* __restrict__ s3,
            __hip_bfloat16* __restrict__ h2) {
    __shared__ __align__(16) ushort s_xb[4 * 816];     // bf16 images (+pad)
    __shared__ __align__(16) ushort s_h1[16 * 1160];   // sectioned, 37.1 KB

    const int tid = threadIdx.x;
    const int b0 = blockIdx.x * 4;
    const int wave = tid >> 6, lane = tid & 63;
    const int l15 = lane & 15, quad = lane >> 4;

    // ---- stage 4 images as bf16 (coalesced float4) ----
    {
        const float4* xg = (const float4*)(x + (size_t)b0 * 784);
        for (int i = tid; i < 784; i += 512) {
            float4 v = xg[i];
            int img = i / 196;
            int p = (i - img * 196) * 4;
            ushort* dst = &s_xb[img * 816 + p];
            dst[0] = f2bfu(v.x); dst[1] = f2bfu(v.y);
            dst[2] = f2bfu(v.z); dst[3] = f2bfu(v.w);
        }
        if (tid < 128) {                    // zero pad (read by pad taps, w=0)
            int img = tid >> 5, k = tid & 31;
            s_xb[img * 816 + 784 + k] = 0;
        }
    }

    // conv1 B-fragments (frag-major: coalesced 1 KB wave loads)
    bf16x8 bw1[2], bw1s[2];
    float bb1[2];
    #pragma unroll
    for (int nt = 0; nt < 2; ++nt) {
        bw1[nt]  = *(const bf16x8*)((const ushort*)wc1f + (nt * 64 + lane) * 8);
        bw1s[nt] = *(const bf16x8*)((const ushort*)wc1s + (nt * 64 + lane) * 8);
        bb1[nt] = b1[nt * 16 + l15];
    }
    __syncthreads();

    // ---- conv1 via MFMA: wave = (img, half). M=576 pool-grouped, N=32 ----
    {
        const int img = wave >> 1, half = wave & 1;
        const int sub = l15 & 3;
        const ushort* srcImg = s_xb + img * 816;
        int offr[4];
        #pragma unroll
        for (int r = 0; r < 4; ++r) {
            int t = quad * 8 + 2 * r;          // even
            int row = (t * 43) >> 8;           // t / 6
            int col = t - 6 * row;             // even
            offr[r] = row * 28 + col;          // even
        }
        const int g0 = l15 >> 3, r0 = l15 & 7;
        #pragma unroll
        for (int ii = 0; ii < 18; ++ii) {
            const int i = half * 18 + ii;
            const int pb = 4 * i + (l15 >> 2);
            const int pi = (pb * 171) >> 11;   // pb / 12
            const int pj = pb - 12 * pi;
            const int base_e = (2 * pi + (sub >> 1)) * 28 + 2 * pj;   // even
            const ushort* p0 = srcImg + base_e;
            union { bf16x8 v; uint u[4]; } A;
            A.u[0] = *(const uint*)(p0 + offr[0]);
            A.u[1] = *(const uint*)(p0 + offr[1]);
            A.u[2] = *(const uint*)(p0 + offr[2]);
            A.u[3] = *(const uint*)(p0 + offr[3]);
            f32x4 z = {0.f, 0.f, 0.f, 0.f};
            f32x4 ce0 = __builtin_amdgcn_mfma_f32_16x16x32_bf16(A.v, bw1[0],  z, 0, 0, 0);
            f32x4 co0 = __builtin_amdgcn_mfma_f32_16x16x32_bf16(A.v, bw1s[0], z, 0, 0, 0);
            f32x4 ce1 = __builtin_amdgcn_mfma_f32_16x16x32_bf16(A.v, bw1[1],  z, 0, 0, 0);
            f32x4 co1 = __builtin_amdgcn_mfma_f32_16x16x32_bf16(A.v, bw1s[1], z, 0, 0, 0);
            const int pbo = 4 * i + quad;
            float m0 = fmaxf(fmaxf(ce0[0], co0[1]), fmaxf(ce0[2], co0[3]));
            float m1 = fmaxf(fmaxf(ce1[0], co1[1]), fmaxf(ce1[2], co1[3]));
            // oc = l15 -> section img*4 + g0 ; oc = 16+l15 -> section img*4+2+g0
            s_h1[(img * 4 + g0) * 1160 + pbo * 8 + r0]     = f2bfu(fmaxf(m0 + bb1[0], 0.f));
            s_h1[(img * 4 + 2 + g0) * 1160 + pbo * 8 + r0] = f2bfu(fmaxf(m1 + bb1[1], 0.f));
        }
    }
    __syncthreads();

    // ---- conv2: 25 tap-GEMMs, K=ic=32; wave = (pool-row, n-half), 4 images
    //      4 A ds_reads + 2 coalesced B loads -> 8 MFMA per tap ----
    const int pr = wave >> 1, nh = wave & 1;
    const int sub2 = l15 & 3;
    const int ci2 = 2 * pr + (sub2 >> 1);
    const int cj2 = 2 * (l15 >> 2) + (sub2 & 1);
    const int posBase = (ci2 * 12 + cj2) * 8;

    f32x4 acc[4][2];                       // [img][ntl]
    float bb2[2];
    #pragma unroll
    for (int ntl = 0; ntl < 2; ++ntl) {
        bb2[ntl] = b2[(nh * 2 + ntl) * 16 + l15];
        #pragma unroll
        for (int img = 0; img < 4; ++img)
            acc[img][ntl] = (f32x4){0.f, 0.f, 0.f, 0.f};
    }

    #pragma unroll
    for (int tap = 0; tap < 25; ++tap) {
        const int ki = tap / 5, kj = tap % 5;          // compile-time
        const int off = (ki * 12 + kj) * 8;
        bf16x8 a[4];
        #pragma unroll
        for (int img = 0; img < 4; ++img)
            a[img] = *(const bf16x8*)&s_h1[(img * 4 + quad) * 1160 + posBase + off];
        #pragma unroll
        for (int ntl = 0; ntl < 2; ++ntl) {
            bf16x8 bf = *(const bf16x8*)((const ushort*)wc2f +
                          ((tap * 4 + nh * 2 + ntl) * 64 + lane) * 8);
            #pragma unroll
            for (int img = 0; img < 4; ++img)
                acc[img][ntl] = __builtin_amdgcn_mfma_f32_16x16x32_bf16(
                    a[img], bf, acc[img][ntl], 0, 0, 0);
        }
    }

    __syncthreads();                       // all waves done reading s_h1

    // ---- epilogue 1: pool+relu+pre-scale, scatter into s_h1-reused LDS
    //      at bucket-sorted slot pos[k] (write-once, no atomics) ----
    // flatten k = oc*16 + pr*4 + quad, oc = (nh*2+ntl)*16 + l15 (img-invariant)
    ushort* s_hs = s_h1;                   // [img][1024], 8 KB of 37 KB
    {
        const int k0 = ((nh * 2 + 0) * 16 + l15) * 16 + pr * 4 + quad;
        const int k1 = ((nh * 2 + 1) * 16 + l15) * 16 + pr * 4 + quad;
        const int p0 = pos[k0], p1 = pos[k1];
        const float sg0 = s3[k0], sg1 = s3[k1];
        #pragma unroll
        for (int img = 0; img < 4; ++img) {
            f32x4 c0 = acc[img][0];
            float m0 = fmaxf(fmaxf(c0[0], c0[1]), fmaxf(c0[2], c0[3]));
            float v0 = fmaxf(m0 + bb2[0], 0.f);
            s_hs[img * 1024 + p0] = f2bfu(v0 * sg0);
            f32x4 c1 = acc[img][1];
            float m1 = fmaxf(fmaxf(c1[0], c1[1]), fmaxf(c1[2], c1[3]));
            float v1 = fmaxf(m1 + bb2[1], 0.f);
            s_hs[img * 1024 + p1] = f2bfu(v1 * sg1);
        }
    }
    __syncthreads();

    // ---- epilogue 2: 512 parallel segment sums -> h2[b][q] (B x 128) ----
    {
        const int img = tid >> 7, q = tid & 127;
        const int a0 = seg[q], n = seg[q + 1] - a0;
        const ushort* src = s_hs + img * 1024 + a0;
        float v = 0.f;
        for (int i = 0; i < n; ++i) v += bfu2f(src[i]);
        h2[(size_t)(b0 + img) * 128 + q] = __float2bfloat16(v);
    }
}

// Fused fc1 (K=128 dense-w3 bf16 MFMA) + fc2 + log_softmax.  [R5 known-good]
// 1024 thr = 16 waves; fc1: wave = 32-col strip (2 n-tiles), 4 kt iters,
// B frag-major; fc2: wave = 1 image, full-wave shuffle reduce.
__global__ __launch_bounds__(1024)
void k_fc(const __hip_bfloat16* __restrict__ A, const __hip_bfloat16* __restrict__ W3d,
          const float* __restrict__ b3, const float* __restrict__ fc2w,
          const float* __restrict__ fc2b, float* __restrict__ out) {
    __shared__ __align__(16) ushort s_A[16 * 136];    // 128 + 8 pad per row
    __shared__ float s_h3[16 * 516];

    const int tid = threadIdx.x;
    const int wave = tid >> 6, lane = tid & 63;
    const int l15 = lane & 15, quad = lane >> 4;
    const int mBase = blockIdx.x * 16;

    // stage A row `wave` into LDS (64 lanes x 4 B = 256 B row)
    {
        const uint* g = (const uint*)(A + (size_t)(mBase + wave) * 128);
        *(uint*)&s_A[wave * 136 + lane * 2] = g[lane];
    }
    __syncthreads();

    f32x4 acc[2];
    acc[0] = (f32x4){0.f, 0.f, 0.f, 0.f};
    acc[1] = (f32x4){0.f, 0.f, 0.f, 0.f};

    const ushort* aP = &s_A[l15 * 136 + quad * 8];
    const ushort* bP0 = (const ushort*)W3d + ((size_t)(wave * 2)     * 4 * 64 + lane) * 8;
    const ushort* bP1 = (const ushort*)W3d + ((size_t)(wave * 2 + 1) * 4 * 64 + lane) * 8;
    #pragma unroll
    for (int kt = 0; kt < 4; ++kt) {
        bf16x8 a = *(const bf16x8*)(aP + kt * 32);
        bf16x8 bf0 = *(const bf16x8*)(bP0 + kt * 512);
        bf16x8 bf1 = *(const bf16x8*)(bP1 + kt * 512);
        acc[0] = __builtin_amdgcn_mfma_f32_16x16x32_bf16(a, bf0, acc[0], 0, 0, 0);
        acc[1] = __builtin_amdgcn_mfma_f32_16x16x32_bf16(a, bf1, acc[1], 0, 0, 0);
    }

    #pragma unroll
    for (int ntl = 0; ntl < 2; ++ntl) {
        int col = wave * 32 + ntl * 16 + l15;
        float bb = b3[col];
        #pragma unroll
        for (int r = 0; r < 4; ++r)
            s_h3[(quad * 4 + r) * 516 + col] = fmaxf(acc[ntl][r] + bb, 0.f);
    }
    __syncthreads();

    // ---- fc2 + log_softmax: wave handles image `wave` ----
    const float* hrow = &s_h3[wave * 516];
    float4 h0 = *(const float4*)&hrow[lane * 8];
    float4 h1 = *(const float4*)&hrow[lane * 8 + 4];
    float lg[10];
    #pragma unroll
    for (int c = 0; c < 10; ++c) {
        float4 w0 = *(const float4*)&fc2w[c * 512 + lane * 8];
        float4 w1 = *(const float4*)&fc2w[c * 512 + lane * 8 + 4];
        float s = h0.x * w0.x + h0.y * w0.y + h0.z * w0.z + h0.w * w0.w
                + h1.x * w1.x + h1.y * w1.y + h1.z * w1.z + h1.w * w1.w;
        s += __shfl_down(s, 32);
        s += __shfl_down(s, 16);
        s += __shfl_down(s, 8);
        s += __shfl_down(s, 4);
        s += __shfl_down(s, 2);
        s += __shfl_down(s, 1);
        lg[c] = s;
    }
    if (lane == 0) {
        float mx = -1e30f;
        #pragma unroll
        for (int c = 0; c < 10; ++c) { lg[c] += fc2b[c]; mx = fmaxf(mx, lg[c]); }
        float sum = 0.f;
        #pragma unroll
        for (int c = 0; c < 10; ++c) sum += expf(lg[c] - mx);
        float lse = mx + logf(sum);
        #pragma unroll
        for (int c = 0; c < 10; ++c)
            out[(size_t)(mBase + wave) * 10 + c] = lg[c] - lse;
    }
}

extern "C" void kernel_launch(void* const* d_in, const int* in_sizes, int n_in,
                              void* d_out, int out_size, void* d_ws, size_t ws_size,
                              hipStream_t stream) {
    const float* x    = (const float*)d_in[0];
    const int*   hi1  = (const int*)d_in[1];
    const int*   hi2  = (const int*)d_in[2];
    const int*   hi3  = (const int*)d_in[3];
    const float* s1   = (const float*)d_in[4];
    const float* s2   = (const float*)d_in[5];
    const float* s3   = (const float*)d_in[6];
    const float* w1   = (const float*)d_in[7];
    const float* b1   = (const float*)d_in[8];
    const float* w2   = (const float*)d_in[9];
    const float* b2   = (const float*)d_in[10];
    const float* w3   = (const float*)d_in[11];
    const float* b3   = (const float*)d_in[12];
    const float* fc2w = (const float*)d_in[13];
    const float* fc2b = (const float*)d_in[14];
    float* out = (float*)d_out;

    const int B = in_sizes[0] / 784;   // 4096

    char* ws = (char*)d_ws;
    __hip_bfloat16* wc1f = (__hip_bfloat16*)(ws + 0);
    __hip_bfloat16* wc1s = (__hip_bfloat16*)(ws + 2048);
    __hip_bfloat16* wc2f = (__hip_bfloat16*)(ws + 4096);
    __hip_bfloat16* W3d  = (__hip_bfloat16*)(ws + 106496);
    int*            seg  = (int*)(ws + 237568);
    int*            pos  = (int*)(ws + 238592);
    __hip_bfloat16* h2   = (__hip_bfloat16*)(ws + 1155072);   // B x 128 bf16

    // blocks 0..231: fragments; block 232: seg/pos builder
    k_reconstruct<<<233, 256, 0, stream>>>(
        w1, w2, w3, hi1, hi2, hi3, s1, s2, wc1f, wc1s, wc2f, W3d, seg, pos);
    k_conv<<<B / 4, 512, 0, stream>>>(x, wc1f, wc1s, wc2f, b1, b2, pos, seg, s3, h2);
    k_fc<<<B / 16, 1024, 0, stream>>>(h2, W3d, b3, fc2w, fc2b, out);
}